// Round 1
// baseline (8198.833 us; speedup 1.0000x reference)
//
#include <hip/hip_runtime.h>
#include <hip/hip_bf16.h>

#define HIDDEN 1024
#define NHEAD 16
#define HEADD 64
#define NLAYER 8
#define SEQL 2048
#define NVOCAB 50272
#define EPSF 1e-5f

typedef __hip_bfloat16 bf16;
typedef __attribute__((ext_vector_type(8))) short short8;
typedef __attribute__((ext_vector_type(4))) float f32x4;

// ---------- helpers ----------

__device__ __forceinline__ unsigned short f2bf(float f) {
  unsigned int u = __float_as_uint(f);
  u += 0x7fffu + ((u >> 16) & 1u);   // round-to-nearest-even
  return (unsigned short)(u >> 16);
}

__device__ __forceinline__ float lanef(float v, int l) {
  return __uint_as_float(__builtin_amdgcn_readlane(__float_as_uint(v), l));
}

__device__ __forceinline__ float block_sum256(float v) {
  __shared__ float sb[4];
  #pragma unroll
  for (int off = 32; off; off >>= 1) v += __shfl_xor(v, off);
  if ((threadIdx.x & 63) == 0) sb[threadIdx.x >> 6] = v;
  __syncthreads();
  return sb[0] + sb[1] + sb[2] + sb[3];
}

// ---------- fp32 -> bf16 weight conversion ----------

__global__ __launch_bounds__(256) void cvt_bf16_k(const float4* __restrict__ in,
                                                  ushort4* __restrict__ out, long n4) {
  long i = (long)blockIdx.x * 256 + threadIdx.x;
  if (i < n4) {
    float4 v = in[i];
    out[i] = make_ushort4(f2bf(v.x), f2bf(v.y), f2bf(v.z), f2bf(v.w));
  }
}

// ---------- embedding + rmsnorm (fp32 out, residual stream) ----------

__global__ __launch_bounds__(256) void embed_rms_k(const int* __restrict__ ids,
                                                   const float* __restrict__ wte,
                                                   float* __restrict__ x) {
  int t = blockIdx.x;
  const float4* row = (const float4*)(wte + (long)ids[t] * HIDDEN);
  float4 v = row[threadIdx.x];
  float ss = block_sum256(v.x * v.x + v.y * v.y + v.z * v.z + v.w * v.w);
  float sc = rsqrtf(ss * (1.0f / HIDDEN) + EPSF);
  float4 o; o.x = v.x * sc; o.y = v.y * sc; o.z = v.z * sc; o.w = v.w * sc;
  ((float4*)(x + (long)t * HIDDEN))[threadIdx.x] = o;
}

// ---------- rmsnorm fp32 -> bf16 (GEMM input) ----------

__global__ __launch_bounds__(256) void rms_bf16_k(const float* __restrict__ x,
                                                  bf16* __restrict__ h) {
  int t = blockIdx.x;
  float4 v = ((const float4*)(x + (long)t * HIDDEN))[threadIdx.x];
  float ss = block_sum256(v.x * v.x + v.y * v.y + v.z * v.z + v.w * v.w);
  float sc = rsqrtf(ss * (1.0f / HIDDEN) + EPSF);
  ((ushort4*)(h + (long)t * HIDDEN))[threadIdx.x] =
      make_ushort4(f2bf(v.x * sc), f2bf(v.y * sc), f2bf(v.z * sc), f2bf(v.w * sc));
}

// ---------- per-head qk rmsnorm + rope ----------
// one wave per (t, h); lane = dim. Writes Qr (pre-scaled by 1/sqrt(64)) and Kr, fp32.

__global__ __launch_bounds__(256) void qknorm_rope_k(const float* __restrict__ qkv,
                                                     float* __restrict__ Qr,
                                                     float* __restrict__ Kr) {
  int lane = threadIdx.x & 63;
  int id = blockIdx.x * 4 + (threadIdx.x >> 6);
  int h = id & (NHEAD - 1);
  int t = id >> 4;
  long base = (long)t * (3 * HIDDEN) + h * HEADD + lane;
  float qv = qkv[base];
  float kv = qkv[base + HIDDEN];
  float sq = qv * qv, sk = kv * kv;
  #pragma unroll
  for (int off = 32; off; off >>= 1) { sq += __shfl_xor(sq, off); sk += __shfl_xor(sk, off); }
  qv *= rsqrtf(sq * (1.0f / HEADD) + EPSF);
  kv *= rsqrtf(sk * (1.0f / HEADD) + EPSF);
  int i = lane >> 1;
  float inv = powf(10000.0f, -(float)i * (1.0f / 32.0f));
  float ang = (float)t * inv;
  float s, c;
  sincosf(ang, &s, &c);
  float qo = __shfl_xor(qv, 1), ko = __shfl_xor(kv, 1);
  float qn, kn;
  if (lane & 1) { qn = qv * s + qo * c; kn = kv * s + ko * c; }   // out[2i+1] = b*s + a*c
  else          { qn = qo * c - qv * s; kn = ko * c - kv * s; }   // out[2i]   = b*c - a*s
  long ob = (long)t * HIDDEN + h * HEADD + lane;
  Qr[ob] = qn * 0.125f;  // fold 1/sqrt(HEAD_DIM) into q
  Kr[ob] = kn;
}

// ---------- flash attention (fp32, online softmax) ----------
// grid (SEQ/4, NHEAD), block 256 = 4 waves; each wave owns one query row.
// K/V chunks of 64 keys staged in LDS with +1 pad (bank-conflict free).

__global__ __launch_bounds__(256) void attn_k(const float* __restrict__ Qr,
                                              const float* __restrict__ Kr,
                                              const float* __restrict__ qkv,
                                              bf16* __restrict__ attn_o) {
  __shared__ float Kt[64 * 65];
  __shared__ float Vt[64 * 65];
  int h = blockIdx.y;
  int w = threadIdx.x >> 6, lane = threadIdx.x & 63;
  int qrow = blockIdx.x * 4 + w;
  float qv = Qr[(long)qrow * HIDDEN + h * HEADD + lane];
  float mrun = -1e30f, lrun = 0.0f, orun = 0.0f;
  int nch = (blockIdx.x * 4 + 3) / 64 + 1;
  for (int c = 0; c < nch; ++c) {
    __syncthreads();
    for (int e = threadIdx.x; e < 1024; e += 256) {
      int kk = e >> 4, d4 = (e & 15) * 4;
      int key = c * 64 + kk;
      float4 kvv = *(const float4*)(Kr + (long)key * HIDDEN + h * HEADD + d4);
      float4 vvv = *(const float4*)(qkv + (long)key * (3 * HIDDEN) + 2 * HIDDEN + h * HEADD + d4);
      float* kd = &Kt[kk * 65 + d4];
      kd[0] = kvv.x; kd[1] = kvv.y; kd[2] = kvv.z; kd[3] = kvv.w;
      float* vd = &Vt[kk * 65 + d4];
      vd[0] = vvv.x; vd[1] = vvv.y; vd[2] = vvv.z; vd[3] = vvv.w;
    }
    __syncthreads();
    if (qrow >= c * 64) {
      const float* krow = &Kt[lane * 65];
      float s = 0.0f;
      #pragma unroll
      for (int d = 0; d < 64; ++d) s += lanef(qv, d) * krow[d];
      int jj = c * 64 + lane;
      s = (jj <= qrow) ? s : -1e30f;
      float cm = s;
      #pragma unroll
      for (int off = 32; off; off >>= 1) cm = fmaxf(cm, __shfl_xor(cm, off));
      float mn = fmaxf(mrun, cm);
      float alpha = __expf(mrun - mn);
      float p = __expf(s - mn);
      float ps = p;
      #pragma unroll
      for (int off = 32; off; off >>= 1) ps += __shfl_xor(ps, off);
      lrun = lrun * alpha + ps;
      float a2 = 0.0f;
      #pragma unroll
      for (int j = 0; j < 64; ++j) a2 += lanef(p, j) * Vt[j * 65 + lane];
      orun = orun * alpha + a2;
      mrun = mn;
    }
  }
  ((unsigned short*)attn_o)[(long)qrow * HIDDEN + h * HEADD + lane] = f2bf(orun / lrun);
}

// ---------- bf16 MFMA GEMM: C[M,N] = A[M,K] @ B[N,K]^T (+ epilogue) ----------
// EPI: 0 = plain fp32 out, 1 = fp32 out += residual, 2 = relu^2 -> bf16 out.
// Block 256 = 4 waves (2x2), 128x128 block tile, 64x64 per wave, direct global frags.

template<int EPI>
__global__ __launch_bounds__(256) void gemm_k(const bf16* __restrict__ A,
                                              const bf16* __restrict__ B,
                                              const float* __restrict__ res,
                                              void* __restrict__ Cv,
                                              int M, int N, int K) {
  int lane = threadIdx.x & 63;
  int wv = threadIdx.x >> 6;
  int fr = lane & 15, quad = lane >> 4;
  int m0 = blockIdx.y * 128 + (wv >> 1) * 64;
  int n0 = blockIdx.x * 128 + (wv & 1) * 64;
  int kq = quad * 8;
  f32x4 acc[4][4] = {};
  const short8 zero8 = {0, 0, 0, 0, 0, 0, 0, 0};
  for (int kk = 0; kk < K; kk += 32) {
    short8 af[4], bfr[4];
    #pragma unroll
    for (int i = 0; i < 4; ++i) {
      af[i] = *(const short8*)(A + (long)(m0 + i * 16 + fr) * K + kk + kq);
      int nr = n0 + i * 16 + fr;
      bfr[i] = (nr < N) ? *(const short8*)(B + (long)nr * K + kk + kq) : zero8;
    }
    #pragma unroll
    for (int i = 0; i < 4; ++i) {
      #pragma unroll
      for (int j = 0; j < 4; ++j) {
        acc[i][j] = __builtin_amdgcn_mfma_f32_16x16x32_bf16(af[i], bfr[j], acc[i][j], 0, 0, 0);
      }
    }
  }
  #pragma unroll
  for (int i = 0; i < 4; ++i) {
    #pragma unroll
    for (int j = 0; j < 4; ++j) {
      int col = n0 + j * 16 + fr;
      if (col < N) {
        #pragma unroll
        for (int tt = 0; tt < 4; ++tt) {
          int rowm = m0 + i * 16 + quad * 4 + tt;
          long idx = (long)rowm * N + col;
          float v = acc[i][j][tt];
          if (EPI == 1) v += res[idx];
          if (EPI == 2) {
            v = fmaxf(v, 0.0f);
            v = v * v;
            ((unsigned short*)Cv)[idx] = f2bf(v);
          } else {
            ((float*)Cv)[idx] = v;
          }
        }
      }
    }
  }
}

// ---------- launch ----------

extern "C" void kernel_launch(void* const* d_in, const int* in_sizes, int n_in,
                              void* d_out, int out_size, void* d_ws, size_t ws_size,
                              hipStream_t stream) {
  const int*   ids  = (const int*)d_in[0];
  const float* wte  = (const float*)d_in[1];
  const float* wqkv = (const float*)d_in[2];
  const float* wo   = (const float*)d_in[3];
  const float* w1   = (const float*)d_in[4];
  const float* w2   = (const float*)d_in[5];
  const float* lmh  = (const float*)d_in[6];

  char* ws = (char*)d_ws;
  size_t off = 0;
  auto alloc = [&](size_t bytes) {
    void* p = ws + off;
    off = (off + bytes + 255) & ~(size_t)255;
    return p;
  };
  bf16*  wqkv_b = (bf16*)alloc((size_t)NLAYER * 3 * HIDDEN * HIDDEN * 2);
  bf16*  wo_b   = (bf16*)alloc((size_t)NLAYER * HIDDEN * HIDDEN * 2);
  bf16*  w1_b   = (bf16*)alloc((size_t)NLAYER * 4 * HIDDEN * HIDDEN * 2);
  bf16*  w2_b   = (bf16*)alloc((size_t)NLAYER * 4 * HIDDEN * HIDDEN * 2);
  bf16*  lm_b   = (bf16*)alloc((size_t)NVOCAB * HIDDEN * 2);
  float* x      = (float*)alloc((size_t)SEQL * HIDDEN * 4);
  bf16*  hbuf   = (bf16*)alloc((size_t)SEQL * HIDDEN * 2);
  float* qkv    = (float*)alloc((size_t)SEQL * 3 * HIDDEN * 4);
  float* Qr     = (float*)alloc((size_t)SEQL * HIDDEN * 4);
  float* Kr     = (float*)alloc((size_t)SEQL * HIDDEN * 4);
  bf16*  attn_o = (bf16*)alloc((size_t)SEQL * HIDDEN * 2);
  bf16*  tbuf   = (bf16*)alloc((size_t)SEQL * 4 * HIDDEN * 2);

  auto cvt = [&](const float* src, bf16* dst, long n) {
    long n4 = n / 4;
    int grid = (int)((n4 + 255) / 256);
    cvt_bf16_k<<<grid, 256, 0, stream>>>((const float4*)src, (ushort4*)dst, n4);
  };
  cvt(wqkv, wqkv_b, (long)NLAYER * 3 * HIDDEN * HIDDEN);
  cvt(wo,   wo_b,   (long)NLAYER * HIDDEN * HIDDEN);
  cvt(w1,   w1_b,   (long)NLAYER * 4 * HIDDEN * HIDDEN);
  cvt(w2,   w2_b,   (long)NLAYER * 4 * HIDDEN * HIDDEN);
  cvt(lmh,  lm_b,   (long)NVOCAB * HIDDEN);

  embed_rms_k<<<SEQL, 256, 0, stream>>>(ids, wte, x);

  for (int l = 0; l < NLAYER; ++l) {
    const bf16* Wq = wqkv_b + (long)l * 3 * HIDDEN * HIDDEN;
    const bf16* Wo = wo_b   + (long)l * HIDDEN * HIDDEN;
    const bf16* W1 = w1_b   + (long)l * 4 * HIDDEN * HIDDEN;
    const bf16* W2 = w2_b   + (long)l * 4 * HIDDEN * HIDDEN;

    rms_bf16_k<<<SEQL, 256, 0, stream>>>(x, hbuf);
    gemm_k<0><<<dim3(3 * HIDDEN / 128, SEQL / 128), 256, 0, stream>>>(
        hbuf, Wq, nullptr, qkv, SEQL, 3 * HIDDEN, HIDDEN);
    qknorm_rope_k<<<SEQL * NHEAD / 4, 256, 0, stream>>>(qkv, Qr, Kr);
    attn_k<<<dim3(SEQL / 4, NHEAD), 256, 0, stream>>>(Qr, Kr, qkv, attn_o);
    gemm_k<1><<<dim3(HIDDEN / 128, SEQL / 128), 256, 0, stream>>>(
        attn_o, Wo, x, x, SEQL, HIDDEN, HIDDEN);
    rms_bf16_k<<<SEQL, 256, 0, stream>>>(x, hbuf);
    gemm_k<2><<<dim3(4 * HIDDEN / 128, SEQL / 128), 256, 0, stream>>>(
        hbuf, W1, nullptr, tbuf, SEQL, 4 * HIDDEN, HIDDEN);
    gemm_k<1><<<dim3(HIDDEN / 128, SEQL / 128), 256, 0, stream>>>(
        tbuf, W2, x, x, SEQL, HIDDEN, 4 * HIDDEN);
  }

  rms_bf16_k<<<SEQL, 256, 0, stream>>>(x, hbuf);
  gemm_k<0><<<dim3((NVOCAB + 127) / 128, SEQL / 128), 256, 0, stream>>>(
      hbuf, lm_b, nullptr, (float*)d_out, SEQL, NVOCAB, HIDDEN);
}